// Round 1
// baseline (95.132 us; speedup 1.0000x reference)
//
#include <hip/hip_runtime.h>
#include <math.h>

// Problem constants (dim=128, B=1, N=1024)
#define DIM 128          // node feature dim
#define H   256          // hidden = 2*dim
#define ROWS 8           // rows per node-encoder block
#define NROWS 1024       // N
#define NODE_BLOCKS (NROWS / ROWS)          // 128
#define ADJ_SIZE (NROWS * NROWS)            // 1048576 floats
#define FILL_BLOCKS (ADJ_SIZE / (256 * 4))  // 1024 blocks of float4 stores

// Key insight: reference's gumbel_softmax over a singleton axis is identically
// 1.0, so adj_matrix = (1.0 > threshold) broadcast — the whole edge-predictor
// (hi/hj/pair GELU/[N,N] matmul, W_e1/W_e2) is dead code for both outputs.
// Output layout: d_out = [adj (1048576 f32), node_feats (131072 f32)].

__global__ __launch_bounds__(256) void fused_graphgen(
    const float* __restrict__ x,
    const float* __restrict__ W1, const float* __restrict__ b1,
    const float* __restrict__ lng, const float* __restrict__ lnb,
    const float* __restrict__ W2, const float* __restrict__ b2,
    const float* __restrict__ thr,
    float* __restrict__ out)
{
    const int blk = blockIdx.x;
    const int tid = threadIdx.x;

    if (blk >= NODE_BLOCKS) {
        // ---- adj fill: constant (1.0 > threshold) over 1M floats ----
        const int fb = blk - NODE_BLOCKS;
        const float a = (1.0f > thr[0]) ? 1.0f : 0.0f;
        float4 v = make_float4(a, a, a, a);
        ((float4*)out)[fb * 256 + tid] = v;
        return;
    }

    // ---- node encoder: 8 rows per block ----
    __shared__ float xs[ROWS * DIM];    // 4 KB
    __shared__ float hbuf[ROWS * H];    // 8 KB
    __shared__ float mu_s[ROWS], ri_s[ROWS];

    // stage 8 rows of x (8*128 = 1024 floats = 256 float4, one per thread)
    const float4* xsrc = (const float4*)(x + (size_t)blk * ROWS * DIM);
    ((float4*)xs)[tid] = xsrc[tid];
    __syncthreads();

    // GEMM1: thread tid owns hidden unit j=tid for all 8 rows.
    // W1 read coalesced (W1[k*256+tid]), xs reads are wave-broadcast.
    float acc[ROWS];
    #pragma unroll
    for (int r = 0; r < ROWS; ++r) acc[r] = 0.0f;
    for (int k = 0; k < DIM; ++k) {
        float w = W1[k * H + tid];
        #pragma unroll
        for (int r = 0; r < ROWS; ++r) acc[r] += xs[r * DIM + k] * w;
    }
    {
        float bb = b1[tid];
        #pragma unroll
        for (int r = 0; r < ROWS; ++r) hbuf[r * H + tid] = acc[r] + bb;
    }
    __syncthreads();

    // LayerNorm stats: 8 rows, one 32-lane group per row (tid>>5 = row).
    {
        int grp = tid >> 5, lane = tid & 31;
        float s = 0.0f, ss = 0.0f;
        #pragma unroll
        for (int m = 0; m < H / 32; ++m) {
            float v = hbuf[grp * H + lane + m * 32];
            s += v; ss += v * v;
        }
        #pragma unroll
        for (int off = 16; off >= 1; off >>= 1) {
            s  += __shfl_down(s,  off, 32);
            ss += __shfl_down(ss, off, 32);
        }
        if (lane == 0) {
            float mu  = s * (1.0f / H);
            float var = ss * (1.0f / H) - mu * mu;
            mu_s[grp] = mu;
            ri_s[grp] = rsqrtf(var + 1e-5f);
        }
    }
    __syncthreads();

    // normalize + affine + exact-erf GELU (matches approximate=False)
    {
        float g_ = lng[tid], bln = lnb[tid];
        #pragma unroll
        for (int r = 0; r < ROWS; ++r) {
            float v  = hbuf[r * H + tid];
            float hn = (v - mu_s[r]) * ri_s[r] * g_ + bln;
            float ge = 0.5f * hn * (1.0f + erff(hn * 0.70710678118654752f));
            hbuf[r * H + tid] = ge;
        }
    }
    __syncthreads();

    // GEMM2: thread -> column i = tid&127, rows r0, r0+2, r0+4, r0+6 (r0 = tid>>7).
    // Each W2 column load (coalesced) is reused for 4 rows; hbuf reads broadcast.
    {
        int i  = tid & 127;
        int r0 = tid >> 7;
        float o[4];
        #pragma unroll
        for (int k = 0; k < 4; ++k) o[k] = 0.0f;
        for (int j = 0; j < H; ++j) {
            float w = W2[j * DIM + i];
            #pragma unroll
            for (int k = 0; k < 4; ++k) o[k] += hbuf[(r0 + 2 * k) * H + j] * w;
        }
        float be = b2[i];
        float* nf = out + ADJ_SIZE + (size_t)blk * ROWS * DIM;
        #pragma unroll
        for (int k = 0; k < 4; ++k) {
            nf[(r0 + 2 * k) * DIM + i] = o[k] + be;
        }
    }
}

extern "C" void kernel_launch(void* const* d_in, const int* in_sizes, int n_in,
                              void* d_out, int out_size, void* d_ws, size_t ws_size,
                              hipStream_t stream) {
    const float* x    = (const float*)d_in[0];
    const float* W1   = (const float*)d_in[1];
    const float* b1   = (const float*)d_in[2];
    const float* lng  = (const float*)d_in[3];
    const float* lnb  = (const float*)d_in[4];
    const float* W2   = (const float*)d_in[5];
    const float* b2   = (const float*)d_in[6];
    // d_in[7..10] = W_e1, b_e1, W_e2, b_e2 — dead code (see comment above)
    const float* thr  = (const float*)d_in[11];
    float* out = (float*)d_out;

    fused_graphgen<<<NODE_BLOCKS + FILL_BLOCKS, 256, 0, stream>>>(
        x, W1, b1, lng, lnb, W2, b2, thr, out);
}

// Round 2
// 84.497 us; speedup vs baseline: 1.1259x; 1.1259x over previous
//
#include <hip/hip_runtime.h>
#include <math.h>

// Problem constants (dim=128, B=1, N=1024)
#define DIM 128          // node feature dim
#define H   256          // hidden = 2*dim
#define ROWS 4           // rows per node-encoder block
#define NROWS 1024       // N
#define NODE_BLOCKS (NROWS / ROWS)          // 256 -> one per CU
#define ADJ_SIZE (NROWS * NROWS)            // 1048576 floats
#define FILL_BLOCKS (ADJ_SIZE / (256 * 4))  // 1024 blocks of float4 stores

// Key insight: reference's gumbel_softmax over a singleton axis is identically
// 1.0, so adj_matrix = (1.0 > threshold) broadcast — the whole edge-predictor
// (hi/hj/pair GELU/[N,N] matmul, W_e1/W_e2) is dead code for both outputs.
// Output layout: d_out = [adj (1048576 f32), node_feats (131072 f32)].
//
// R2 structure: 256 node blocks (one per CU) + 1024 fill blocks co-resident
// for latency hiding. x read via wave-uniform scalar loads (s_load path),
// W1/W2 loads batched via unroll so vmcnt pipelines instead of serializing.

__global__ __launch_bounds__(256) void fused_graphgen(
    const float* __restrict__ x,
    const float* __restrict__ W1, const float* __restrict__ b1,
    const float* __restrict__ lng, const float* __restrict__ lnb,
    const float* __restrict__ W2, const float* __restrict__ b2,
    const float* __restrict__ thr,
    float* __restrict__ out)
{
    const int blk = blockIdx.x;
    const int tid = threadIdx.x;

    if (blk >= NODE_BLOCKS) {
        // ---- adj fill: constant (1.0 > threshold) over 1M floats ----
        const int fb = blk - NODE_BLOCKS;
        const float a = (1.0f > thr[0]) ? 1.0f : 0.0f;
        ((float4*)out)[fb * 256 + tid] = make_float4(a, a, a, a);
        return;
    }

    // ---- node encoder: 4 rows per block ----
    __shared__ float hbuf[ROWS * H];   // 4 KB
    __shared__ float red[ROWS * DIM];  // 2 KB, GEMM2 split-j partials

    const float* xr = x + (size_t)blk * ROWS * DIM;  // wave-uniform base

    // GEMM1: thread tid owns hidden unit j=tid for all 4 rows.
    // x reads are block-uniform -> scalar loads; W1[k*H+tid] coalesced.
    float a0 = 0.f, a1 = 0.f, a2 = 0.f, a3 = 0.f;
    #pragma unroll 4
    for (int k4 = 0; k4 < DIM / 4; ++k4) {
        const int k = k4 * 4;
        const float4 x0 = *(const float4*)(xr + 0 * DIM + k);
        const float4 x1 = *(const float4*)(xr + 1 * DIM + k);
        const float4 x2 = *(const float4*)(xr + 2 * DIM + k);
        const float4 x3 = *(const float4*)(xr + 3 * DIM + k);
        const float w0 = W1[(k + 0) * H + tid];
        const float w1 = W1[(k + 1) * H + tid];
        const float w2 = W1[(k + 2) * H + tid];
        const float w3 = W1[(k + 3) * H + tid];
        a0 += x0.x * w0 + x0.y * w1 + x0.z * w2 + x0.w * w3;
        a1 += x1.x * w0 + x1.y * w1 + x1.z * w2 + x1.w * w3;
        a2 += x2.x * w0 + x2.y * w1 + x2.z * w2 + x2.w * w3;
        a3 += x3.x * w0 + x3.y * w1 + x3.z * w2 + x3.w * w3;
    }
    {
        const float bb = b1[tid];
        hbuf[0 * H + tid] = a0 + bb;
        hbuf[1 * H + tid] = a1 + bb;
        hbuf[2 * H + tid] = a2 + bb;
        hbuf[3 * H + tid] = a3 + bb;
    }
    __syncthreads();

    // LayerNorm + GELU: wave w owns row w (4 waves, 4 rows). Each lane holds
    // 4 consecutive columns as float4; 64-lane butterfly reduction.
    {
        const int w = tid >> 6, lane = tid & 63;
        float4 v = ((float4*)hbuf)[w * (H / 4) + lane];
        float s  = v.x + v.y + v.z + v.w;
        float ss = v.x * v.x + v.y * v.y + v.z * v.z + v.w * v.w;
        #pragma unroll
        for (int m = 32; m >= 1; m >>= 1) {
            s  += __shfl_xor(s,  m, 64);
            ss += __shfl_xor(ss, m, 64);
        }
        const float mu = s * (1.0f / H);
        const float ri = rsqrtf(ss * (1.0f / H) - mu * mu + 1e-5f);
        const float4 g4 = ((const float4*)lng)[lane];
        const float4 b4 = ((const float4*)lnb)[lane];
        float t;
        t = (v.x - mu) * ri * g4.x + b4.x; v.x = 0.5f * t * (1.0f + erff(t * 0.70710678118654752f));
        t = (v.y - mu) * ri * g4.y + b4.y; v.y = 0.5f * t * (1.0f + erff(t * 0.70710678118654752f));
        t = (v.z - mu) * ri * g4.z + b4.z; v.z = 0.5f * t * (1.0f + erff(t * 0.70710678118654752f));
        t = (v.w - mu) * ri * g4.w + b4.w; v.w = 0.5f * t * (1.0f + erff(t * 0.70710678118654752f));
        ((float4*)hbuf)[w * (H / 4) + lane] = v;
    }
    __syncthreads();

    // GEMM2 split-j: thread -> (col i = tid&127, j-half h = tid>>7).
    // Each half sums 128 j's for all 4 rows; halves combined via LDS.
    // hbuf reads are broadcast ds_read_b128; W2[j*DIM+i] coalesced.
    {
        const int i = tid & 127, h = tid >> 7;
        float o0 = 0.f, o1 = 0.f, o2 = 0.f, o3 = 0.f;
        #pragma unroll 4
        for (int j4 = 0; j4 < 32; ++j4) {
            const int j = h * 128 + j4 * 4;
            const float4 h0 = ((float4*)hbuf)[(0 * H + j) >> 2];
            const float4 h1 = ((float4*)hbuf)[(1 * H + j) >> 2];
            const float4 h2 = ((float4*)hbuf)[(2 * H + j) >> 2];
            const float4 h3 = ((float4*)hbuf)[(3 * H + j) >> 2];
            const float w0 = W2[(j + 0) * DIM + i];
            const float w1 = W2[(j + 1) * DIM + i];
            const float w2 = W2[(j + 2) * DIM + i];
            const float w3 = W2[(j + 3) * DIM + i];
            o0 += h0.x * w0 + h0.y * w1 + h0.z * w2 + h0.w * w3;
            o1 += h1.x * w0 + h1.y * w1 + h1.z * w2 + h1.w * w3;
            o2 += h2.x * w0 + h2.y * w1 + h2.z * w2 + h2.w * w3;
            o3 += h3.x * w0 + h3.y * w1 + h3.z * w2 + h3.w * w3;
        }
        if (h == 1) {  // red[r*DIM+i]: lane i -> bank i%32, conflict-free
            red[0 * DIM + i] = o0;
            red[1 * DIM + i] = o1;
            red[2 * DIM + i] = o2;
            red[3 * DIM + i] = o3;
        }
        __syncthreads();
        if (h == 0) {
            const float be = b2[i];
            float* nf = out + ADJ_SIZE + (size_t)blk * ROWS * DIM;
            nf[0 * DIM + i] = o0 + red[0 * DIM + i] + be;
            nf[1 * DIM + i] = o1 + red[1 * DIM + i] + be;
            nf[2 * DIM + i] = o2 + red[2 * DIM + i] + be;
            nf[3 * DIM + i] = o3 + red[3 * DIM + i] + be;
        }
    }
}

extern "C" void kernel_launch(void* const* d_in, const int* in_sizes, int n_in,
                              void* d_out, int out_size, void* d_ws, size_t ws_size,
                              hipStream_t stream) {
    const float* x    = (const float*)d_in[0];
    const float* W1   = (const float*)d_in[1];
    const float* b1   = (const float*)d_in[2];
    const float* lng  = (const float*)d_in[3];
    const float* lnb  = (const float*)d_in[4];
    const float* W2   = (const float*)d_in[5];
    const float* b2   = (const float*)d_in[6];
    // d_in[7..10] = W_e1, b_e1, W_e2, b_e2 — dead code (see comment above)
    const float* thr  = (const float*)d_in[11];
    float* out = (float*)d_out;

    fused_graphgen<<<NODE_BLOCKS + FILL_BLOCKS, 256, 0, stream>>>(
        x, W1, b1, lng, lnb, W2, b2, thr, out);
}